// Round 3
// baseline (282.548 us; speedup 1.0000x reference)
//
#include <hip/hip_runtime.h>
#include <hip/hip_bf16.h>

#define NROWS 256
#define INF 768
#define NSHORT 2000
#define NHEAD 2003
#define PSTRIDE 1024   // per-row partial-slot stride (845 slots used)

typedef __attribute__((ext_vector_type(8))) short  s16x8;
typedef __attribute__((ext_vector_type(4))) short  s16x4;
typedef __attribute__((ext_vector_type(4))) float  f32x4;
typedef __attribute__((ext_vector_type(8))) float  f32x8;

__device__ __forceinline__ float sigf(float z) { return 1.f / (1.f + __expf(-z)); }
__device__ __forceinline__ float softplusf(float z) {
    return fmaxf(z, 0.f) + __logf(1.f + __expf(-fabsf(z)));
}
__device__ __forceinline__ float qreduce16(float v) {
    v += __shfl_xor(v, 1); v += __shfl_xor(v, 2);
    v += __shfl_xor(v, 4); v += __shfl_xor(v, 8);
    return v;
}
__device__ __forceinline__ float wreduce64(float v) {
    v += __shfl_xor(v, 1);  v += __shfl_xor(v, 2);  v += __shfl_xor(v, 4);
    v += __shfl_xor(v, 8);  v += __shfl_xor(v, 16); v += __shfl_xor(v, 32);
    return v;
}
__device__ __forceinline__ short bfc(float x) {
    union { __hip_bfloat16 h; short s; } u; u.h = __float2bfloat16(x); return u.s;
}

// Streaming MFMA GEMM: C[256,N] = A[256,K](bf16) * W[N,K](f32 -> bf16 on the fly).
// Wave = 16 rows x 64 cols. A-frags fully register-resident (K32*4 VGPRs).
// W streamed global->reg in B-frag layout (per 16 rows: 128B contiguous), 1-chunk prefetch.
// NO LDS, NO barriers. MODE 0: store h(f32). MODE 1: rowsum softplus (col<NSHORT).
// MODE 2: rowsum -max(log1p(-r*sig(z)),-100). MODE 1/2 write part[row*pstride+pslot].
template <int K32, int MODE>
__device__ __forceinline__ void stream_gemm(
    const __hip_bfloat16* __restrict__ A,
    const float* __restrict__ W, int N,
    int row0, int tile0, int ntiles,
    float* __restrict__ outH, int ldH,
    float* __restrict__ part, int pstride, int pslot,
    const float* __restrict__ rootlogit, int ci)
{
    const int t = threadIdx.x;
    const int wave = t >> 6, lane = t & 63;
    const int quad = lane >> 4, l16 = lane & 15;
    const int wrow0 = row0 + wave * 16;
    const int K = K32 * 32;

    // Preload A fragments: lane holds A[m=l16][k=quad*8+j] per 32-k chunk.
    s16x8 af[K32];
    const __hip_bfloat16* arow = A + (size_t)(wrow0 + l16) * K + quad * 8;
#pragma unroll
    for (int j = 0; j < K32; j++) af[j] = *(const s16x8*)(arow + j * 32);

    float rv[4], rs[4];
#pragma unroll
    for (int r = 0; r < 4; r++) rs[r] = 0.f;
    if (MODE == 2) {
#pragma unroll
        for (int r = 0; r < 4; r++)
            rv[r] = sigf(rootlogit[(wrow0 + quad * 4 + r) * 3 + ci]);
    }

    for (int tt = 0; tt < ntiles; tt++) {
        const int col0 = (tile0 + tt) * 64;
        int col[4];
        const float* wp[4];
#pragma unroll
        for (int ct = 0; ct < 4; ct++) {
            col[ct] = col0 + ct * 16 + l16;
            const int cr = col[ct] < N ? col[ct] : N - 1;  // clamp: no OOB read
            wp[ct] = W + (size_t)cr * K + quad * 8;
        }
        f32x4 acc[4];
#pragma unroll
        for (int ct = 0; ct < 4; ct++) acc[ct] = (f32x4){0.f, 0.f, 0.f, 0.f};

        f32x8 wf[4];
#pragma unroll
        for (int ct = 0; ct < 4; ct++) wf[ct] = *(const f32x8*)(wp[ct]);

#pragma unroll
        for (int j = 0; j < K32; j++) {
            f32x8 wn[4];
            if (j + 1 < K32) {
#pragma unroll
                for (int ct = 0; ct < 4; ct++)
                    wn[ct] = *(const f32x8*)(wp[ct] + (size_t)(j + 1) * 32);
            }
            s16x8 wb[4];
#pragma unroll
            for (int ct = 0; ct < 4; ct++) {
#pragma unroll
                for (int i = 0; i < 8; i++) wb[ct][i] = bfc(wf[ct][i]);
            }
#pragma unroll
            for (int ct = 0; ct < 4; ct++)
                acc[ct] = __builtin_amdgcn_mfma_f32_16x16x32_bf16(af[j], wb[ct], acc[ct], 0, 0, 0);
            if (j + 1 < K32) {
#pragma unroll
                for (int ct = 0; ct < 4; ct++) wf[ct] = wn[ct];
            }
        }

        if (MODE == 0) {
#pragma unroll
            for (int ct = 0; ct < 4; ct++) {
                if (col[ct] < N) {
#pragma unroll
                    for (int r = 0; r < 4; r++)
                        outH[(size_t)(wrow0 + quad * 4 + r) * ldH + col[ct]] = acc[ct][r];
                }
            }
        } else if (MODE == 1) {
#pragma unroll
            for (int ct = 0; ct < 4; ct++) {
                if (col[ct] < NSHORT) {
#pragma unroll
                    for (int r = 0; r < 4; r++) rs[r] += softplusf(acc[ct][r]);
                }
            }
        } else {
#pragma unroll
            for (int ct = 0; ct < 4; ct++) {
                if (col[ct] < N) {
#pragma unroll
                    for (int r = 0; r < 4; r++) {
                        const float p = rv[r] * sigf(acc[ct][r]);
                        rs[r] += -fmaxf(__logf(1.f - p), -100.f);
                    }
                }
            }
        }
    }

    if (MODE >= 1) {
#pragma unroll
        for (int r = 0; r < 4; r++) {
            const float s = qreduce16(rs[r]);
            if (l16 == 0)
                part[(size_t)(wrow0 + quad * 4 + r) * pstride + pslot] = s;
        }
    }
}

// cvt x->bf16 (blocks 0..191) + exact fp32 root logits (blocks 192..447)
__global__ __launch_bounds__(256) void k_pre(const float* __restrict__ x,
                                             const float* __restrict__ headW,
                                             __hip_bfloat16* __restrict__ xb,
                                             float* __restrict__ rootlogit) {
    const int bx = blockIdx.x;
    if (bx < 192) {
        const int i = (bx * 256 + threadIdx.x) * 4;
        const float4 v = *(const float4*)(x + i);
        s16x4 o;
        o[0] = bfc(v.x); o[1] = bfc(v.y); o[2] = bfc(v.z); o[3] = bfc(v.w);
        *(s16x4*)(xb + i) = o;
    } else {
        const int row = bx - 192;
        const int wave = threadIdx.x >> 6, lane = threadIdx.x & 63;
        if (wave < 3) {
            const float* xr = x + row * INF;
            const float* wr = headW + (size_t)(NSHORT + wave) * INF;
            float s = 0.f;
            for (int k = lane; k < INF; k += 64) s += xr[k] * wr[k];
            s = wreduce64(s);
            if (lane == 0) rootlogit[row * 3 + wave] = s;
        }
    }
}

// head softplus partials (128 blocks) + w1 GEMMs (44 blocks)
__global__ __launch_bounds__(256, 2) void k_mm1(const __hip_bfloat16* __restrict__ xb,
                                                const float* __restrict__ headW,
                                                const float* w10, const float* w11, const float* w12,
                                                float* __restrict__ phead,
                                                float* h0, float* h1, float* h2) {
    const int bx = blockIdx.x;
    if (bx < 128) {          // head: 4 rowgroups x 32 tiles
        const int rg = bx >> 5, tile = bx & 31;
        stream_gemm<24, 1>(xb, headW, NHEAD, rg * 64, tile, 1,
                           nullptr, 0, phead, 32, tile, nullptr, 0);
    } else if (bx < 152) {   // w1 c0: 4 x 6
        const int b = bx - 128, rg = b / 6, tile = b % 6;
        stream_gemm<24, 0>(xb, w10, 384, rg * 64, tile, 1,
                           h0, 384, nullptr, 0, 0, nullptr, 0);
    } else if (bx < 164) {   // w1 c1: 4 x 3
        const int b = bx - 152, rg = b / 3, tile = b % 3;
        stream_gemm<24, 0>(xb, w11, 192, rg * 64, tile, 1,
                           h1, 192, nullptr, 0, 0, nullptr, 0);
    } else {                 // w1 c2: 4 x 2
        const int b = bx - 164, rg = b / 2, tile = b % 2;
        stream_gemm<24, 0>(xb, w12, 96, rg * 64, tile, 1,
                           h2, 96, nullptr, 0, 0, nullptr, 0);
    }
}

__global__ __launch_bounds__(256) void k_ln(const float* h0, const float* h1, const float* h2,
                                            const float* g0, const float* g1, const float* g2,
                                            const float* b0, const float* b1, const float* b2,
                                            __hip_bfloat16* o0, __hip_bfloat16* o1,
                                            __hip_bfloat16* o2) {
    const int task = blockIdx.x * 4 + (threadIdx.x >> 6);  // 0..767
    const int ci = task >> 8, row = task & 255, lane = threadIdx.x & 63;
    const float *h, *g, *bb; __hip_bfloat16* o; int hsz;
    if (ci == 0)      { h = h0; g = g0; bb = b0; o = o0; hsz = 384; }
    else if (ci == 1) { h = h1; g = g1; bb = b1; o = o1; hsz = 192; }
    else              { h = h2; g = g2; bb = b2; o = o2; hsz = 96;  }
    const float* hr = h + row * hsz;
    float s = 0.f, s2 = 0.f;
    for (int k = lane; k < hsz; k += 64) { const float v = hr[k]; s += v; s2 += v * v; }
    s = wreduce64(s); s2 = wreduce64(s2);
    const float mu = s / hsz;
    const float var = s2 / hsz - mu * mu;
    const float rsn = rsqrtf(var + 1e-5f);
    for (int k = lane; k < hsz; k += 64) {
        const float v = (hr[k] - mu) * rsn * g[k] + bb[k];
        o[row * hsz + k] = __float2bfloat16(fmaxf(v, 0.f));
    }
}

// BCE dense partials (3380 GEMM blocks) + per-row target corrections (256 blocks)
__global__ __launch_bounds__(256, 2) void k_bce(const __hip_bfloat16* hb0,
                                                const __hip_bfloat16* hb1,
                                                const __hip_bfloat16* hb2,
                                                const float* w20, const float* w21, const float* w22,
                                                float* __restrict__ part,
                                                const float* __restrict__ rootlogit,
                                                const float* __restrict__ x,
                                                const float* __restrict__ headW,
                                                const int* __restrict__ target,
                                                float* __restrict__ corrbuf) {
    const int bx = blockIdx.x;
    if (bx < 628) {              // c0: 157 stripes x 4 rg, ntiles=1 (10000 cols)
        const int rg = bx / 157, stripe = bx % 157;
        stream_gemm<12, 2>(hb0, w20, 10000, rg * 64, stripe, 1,
                           nullptr, 0, part, PSTRIDE, stripe, rootlogit, 0);
    } else if (bx < 1504) {      // c1: 219 stripes x 4 rg, ntiles=2 (28000 cols)
        const int b = bx - 628, rg = b / 219, stripe = b % 219;
        stream_gemm<6, 2>(hb1, w21, 28000, rg * 64, stripe * 2, 2,
                          nullptr, 0, part, PSTRIDE, 157 + stripe, rootlogit, 1);
    } else if (bx < 3380) {      // c2: 469 stripes x 4 rg, ntiles=2 (60000 cols)
        const int b = bx - 1504, rg = b / 469, stripe = b % 469;
        stream_gemm<3, 2>(hb2, w22, 60000, rg * 64, stripe * 2, 2,
                          nullptr, 0, part, PSTRIDE, 376 + stripe, rootlogit, 2);
    } else {                     // corrections: one block per row
        const int row = bx - 3380;
        const int t = threadIdx.x, wave = t >> 6, lane = t & 63;
        __shared__ float sx[INF];
        __shared__ __hip_bfloat16 shb[384 + 192 + 96];
        __shared__ int st[20];
        __shared__ float scorr[4];  // [0..2] cluster corr, [3] head corr
        for (int i = t; i < INF; i += 256) sx[i] = x[row * INF + i];
        for (int i = t; i < 384; i += 256) shb[i] = hb0[row * 384 + i];
        for (int i = t; i < 192; i += 256) shb[384 + i] = hb1[row * 192 + i];
        for (int i = t; i < 96; i += 256)  shb[576 + i] = hb2[row * 96 + i];
        if (t < 20) st[t] = target[row * 20 + t];
        if (t < 4) scorr[t] = 0.f;
        __syncthreads();
        for (int l = wave; l < 20; l += 4) {
            const int tg = st[l];
            bool dup = false;
            for (int m = 0; m < l; m++) dup |= (st[m] == tg);
            if (dup) continue;
            if (tg < NSHORT) {
                // exact fp32 head logit; y=1 term: -z
                const float* wr = headW + (size_t)tg * INF;
                float z = 0.f;
                for (int k = lane; k < INF; k += 64) z += sx[k] * wr[k];
                z = wreduce64(z);
                if (lane == 0) atomicAdd(&scorr[3], -z);
            } else {
                int ci, low, hsz, hoff; const float* w2;
                if (tg < 12000)      { ci = 0; low = 2000;  hsz = 384; hoff = 0;   w2 = w20; }
                else if (tg < 40000) { ci = 1; low = 12000; hsz = 192; hoff = 384; w2 = w21; }
                else                 { ci = 2; low = 40000; hsz = 96;  hoff = 576; w2 = w22; }
                const float* wr = w2 + (size_t)(tg - low) * hsz;
                float z = 0.f;
                for (int k = lane; k < hsz; k += 64)
                    z += __bfloat162float(shb[hoff + k]) * wr[k];
                z = wreduce64(z);
                if (lane == 0) {
                    const float rvv = sigf(rootlogit[row * 3 + ci]);
                    const float p = rvv * sigf(z);
                    atomicAdd(&scorr[ci],
                              -fmaxf(__logf(p), -100.f) + fmaxf(__logf(1.f - p), -100.f));
                }
            }
        }
        __syncthreads();
        if (t < 4) corrbuf[row * 4 + t] = scorr[t];
    }
}

// Per-row finalize: reduce partials, apply activity logic, atomicAdd mean into out.
__global__ __launch_bounds__(256) void k_red(const float* __restrict__ part,
                                             const float* __restrict__ phead,
                                             const float* __restrict__ corrbuf,
                                             const float* __restrict__ rootlogit,
                                             const int* __restrict__ target,
                                             float* __restrict__ out) {
    const int row = blockIdx.x, t = threadIdx.x;
    const int wave = t >> 6, lane = t & 63;
    const float* pr = part + (size_t)row * PSTRIDE;
    float c0 = 0.f, c1 = 0.f, c2 = 0.f, hs = 0.f;
    for (int i = t; i < 845; i += 256) {
        const float v = pr[i];
        if (i < 157) c0 += v; else if (i < 376) c1 += v; else c2 += v;
    }
    if (t < 32) hs = phead[row * 32 + t];
    c0 = wreduce64(c0); c1 = wreduce64(c1); c2 = wreduce64(c2); hs = wreduce64(hs);
    __shared__ float red[4][4];
    if (lane == 0) { red[0][wave] = c0; red[1][wave] = c1; red[2][wave] = c2; red[3][wave] = hs; }
    __syncthreads();
    if (t == 0) {
        float cc[3];
        for (int i = 0; i < 3; i++) cc[i] = red[i][0] + red[i][1] + red[i][2] + red[i][3];
        float hsum = red[3][0] + red[3][1] + red[3][2] + red[3][3] + corrbuf[row * 4 + 3];
        bool act[3] = {false, false, false};
        for (int l = 0; l < 20; l++) {
            const int tg = target[row * 20 + l];
            if (tg >= 2000) {
                if (tg < 12000) act[0] = true;
                else if (tg < 40000) act[1] = true;
                else act[2] = true;
            }
        }
        float total = 0.f, num = 2000.f;
        const float csz[3] = {10000.f, 28000.f, 60000.f};
        for (int i = 0; i < 3; i++) {
            if (act[i]) { total += cc[i] + corrbuf[row * 4 + i]; num += csz[i]; }
            else        { hsum += softplusf(rootlogit[row * 3 + i]); num += 1.f; }
        }
        atomicAdd(out, (hsum + total) / num * (1.f / 256.f));
    }
}

extern "C" void kernel_launch(void* const* d_in, const int* in_sizes, int n_in,
                              void* d_out, int out_size, void* d_ws, size_t ws_size,
                              hipStream_t stream) {
    const float* x      = (const float*)d_in[0];
    const float* headW  = (const float*)d_in[1];
    const int*   target = (const int*)d_in[2];
    const float* w10 = (const float*)d_in[3];
    const float* g0  = (const float*)d_in[4];
    const float* b0  = (const float*)d_in[5];
    const float* w20 = (const float*)d_in[6];
    const float* w11 = (const float*)d_in[7];
    const float* g1  = (const float*)d_in[8];
    const float* b1  = (const float*)d_in[9];
    const float* w21 = (const float*)d_in[10];
    const float* w12 = (const float*)d_in[11];
    const float* g2  = (const float*)d_in[12];
    const float* b2  = (const float*)d_in[13];
    const float* w22 = (const float*)d_in[14];
    float* out = (float*)d_out;

    char* ws = (char*)d_ws;
    size_t off = 0;
    auto carve = [&](size_t bytes) -> void* {
        void* p = ws + off;
        off += (bytes + 255) & ~(size_t)255;
        return p;
    };
    __hip_bfloat16* xb  = (__hip_bfloat16*)carve((size_t)256 * INF * 2);
    float* h0           = (float*)carve((size_t)256 * 384 * 4);
    float* h1           = (float*)carve((size_t)256 * 192 * 4);
    float* h2           = (float*)carve((size_t)256 * 96 * 4);
    __hip_bfloat16* hb0 = (__hip_bfloat16*)carve((size_t)256 * 384 * 2);
    __hip_bfloat16* hb1 = (__hip_bfloat16*)carve((size_t)256 * 192 * 2);
    __hip_bfloat16* hb2 = (__hip_bfloat16*)carve((size_t)256 * 96 * 2);
    float* rootlogit    = (float*)carve((size_t)256 * 3 * 4);
    float* phead        = (float*)carve((size_t)256 * 32 * 4);
    float* part         = (float*)carve((size_t)256 * PSTRIDE * 4);
    float* corrbuf      = (float*)carve((size_t)256 * 4 * 4);

    hipMemsetAsync(out, 0, sizeof(float), stream);

    k_pre<<<448, 256, 0, stream>>>(x, headW, xb, rootlogit);
    k_mm1<<<172, 256, 0, stream>>>(xb, headW, w10, w11, w12, phead, h0, h1, h2);
    k_ln<<<192, 256, 0, stream>>>(h0, h1, h2, g0, g1, g2, b0, b1, b2, hb0, hb1, hb2);
    k_bce<<<3636, 256, 0, stream>>>(hb0, hb1, hb2, w20, w21, w22, part, rootlogit,
                                    x, headW, target, corrbuf);
    k_red<<<256, 256, 0, stream>>>(part, phead, corrbuf, rootlogit, target, out);

    (void)in_sizes; (void)n_in; (void)out_size; (void)ws_size;
}

// Round 4
// 256.553 us; speedup vs baseline: 1.1013x; 1.1013x over previous
//
#include <hip/hip_runtime.h>
#include <hip/hip_bf16.h>

#define INF 768
#define NSHORT 2000
#define NHEAD 2003
#define PSTRIDE 1536   // per-row partial slots (1533 used: 157 c0, 438 c1, 938 c2)

typedef __attribute__((ext_vector_type(8))) short  s16x8;
typedef __attribute__((ext_vector_type(4))) short  s16x4;
typedef __attribute__((ext_vector_type(4))) float  f32x4;
typedef __attribute__((ext_vector_type(8))) float  f32x8;

__device__ __forceinline__ float sigf(float z) { return 1.f / (1.f + __expf(-z)); }
__device__ __forceinline__ float softplusf(float z) {
    return fmaxf(z, 0.f) + __logf(1.f + __expf(-fabsf(z)));
}
__device__ __forceinline__ float qreduce16(float v) {
    v += __shfl_xor(v, 1); v += __shfl_xor(v, 2);
    v += __shfl_xor(v, 4); v += __shfl_xor(v, 8);
    return v;
}
__device__ __forceinline__ float wreduce64(float v) {
    v += __shfl_xor(v, 1);  v += __shfl_xor(v, 2);  v += __shfl_xor(v, 4);
    v += __shfl_xor(v, 8);  v += __shfl_xor(v, 16); v += __shfl_xor(v, 32);
    return v;
}
__device__ __forceinline__ short bfc(float x) {
    union { __hip_bfloat16 h; short s; } u; u.h = __float2bfloat16(x); return u.s;
}

// Streaming MFMA GEMM, one block = 256 rows x 64-col stripe, 4 waves x 64 rows each.
// All 4 waves load identical W fragments (L1-dedup => W read once per block).
// Double-buffered register pipeline on W (f32x8 -> bf16 in-loop) and A (s16x8).
// No LDS, no barriers. MODE 0: store h. MODE 1: rowsum softplus (col<NSHORT).
// MODE 2: rowsum -max(log1p(-r*sig(z)),-100).
template <int K32, int MODE>
__device__ __forceinline__ void core_gemm(
    const __hip_bfloat16* __restrict__ A,   // [256,K] bf16
    const float* __restrict__ W, int N,     // [N,K] f32
    int stripe,
    float* __restrict__ outH, int ldH,
    float* __restrict__ part, int pstride, int pslot,
    const float* __restrict__ rootlogit, int ci)
{
    const int t = threadIdx.x;
    const int wave = t >> 6, lane = t & 63;
    const int quad = lane >> 4, l16 = lane & 15;
    const int row0 = wave * 64;
    const int K = K32 * 32;
    const int col0 = stripe * 64;

    int col[4];
    const float* wp[4];
#pragma unroll
    for (int ct = 0; ct < 4; ct++) {
        col[ct] = col0 + ct * 16 + l16;
        const int cr = col[ct] < N ? col[ct] : N - 1;  // clamp: no OOB
        wp[ct] = W + (size_t)cr * K + quad * 8;
    }
    const __hip_bfloat16* ap[4];
#pragma unroll
    for (int rt = 0; rt < 4; rt++)
        ap[rt] = A + (size_t)(row0 + rt * 16 + l16) * K + quad * 8;

    f32x8 wf[2][4];
    s16x8 af[2][4];
#pragma unroll
    for (int ct = 0; ct < 4; ct++) wf[0][ct] = *(const f32x8*)(wp[ct]);
#pragma unroll
    for (int rt = 0; rt < 4; rt++) af[0][rt] = *(const s16x8*)(ap[rt]);

    f32x4 acc[4][4];
#pragma unroll
    for (int rt = 0; rt < 4; rt++)
#pragma unroll
        for (int ct = 0; ct < 4; ct++) acc[rt][ct] = (f32x4){0.f, 0.f, 0.f, 0.f};

#pragma unroll 4
    for (int j = 0; j < K32; j++) {
        const int b = j & 1, nb = b ^ 1;
        if (j + 1 < K32) {
#pragma unroll
            for (int ct = 0; ct < 4; ct++)
                wf[nb][ct] = *(const f32x8*)(wp[ct] + (size_t)(j + 1) * 32);
#pragma unroll
            for (int rt = 0; rt < 4; rt++)
                af[nb][rt] = *(const s16x8*)(ap[rt] + (size_t)(j + 1) * 32);
        }
        s16x8 wb[4];
#pragma unroll
        for (int ct = 0; ct < 4; ct++)
#pragma unroll
            for (int i = 0; i < 8; i++) wb[ct][i] = bfc(wf[b][ct][i]);
#pragma unroll
        for (int rt = 0; rt < 4; rt++)
#pragma unroll
            for (int ct = 0; ct < 4; ct++)
                acc[rt][ct] = __builtin_amdgcn_mfma_f32_16x16x32_bf16(
                    af[b][rt], wb[ct], acc[rt][ct], 0, 0, 0);
    }

    if (MODE == 0) {
#pragma unroll
        for (int rt = 0; rt < 4; rt++)
#pragma unroll
            for (int ct = 0; ct < 4; ct++) {
                if (col[ct] < N) {
#pragma unroll
                    for (int r = 0; r < 4; r++)
                        outH[(size_t)(row0 + rt * 16 + quad * 4 + r) * ldH + col[ct]] =
                            acc[rt][ct][r];
                }
            }
    } else if (MODE == 1) {
#pragma unroll
        for (int rt = 0; rt < 4; rt++) {
#pragma unroll
            for (int r = 0; r < 4; r++) {
                const int row = row0 + rt * 16 + quad * 4 + r;
                float s = 0.f;
#pragma unroll
                for (int ct = 0; ct < 4; ct++)
                    if (col[ct] < NSHORT) s += softplusf(acc[rt][ct][r]);
                s = qreduce16(s);
                if (l16 == 0) part[(size_t)row * pstride + pslot] = s;
            }
        }
    } else {
#pragma unroll
        for (int rt = 0; rt < 4; rt++) {
#pragma unroll
            for (int r = 0; r < 4; r++) {
                const int row = row0 + rt * 16 + quad * 4 + r;
                const float rv = sigf(rootlogit[row * 3 + ci]);
                float s = 0.f;
#pragma unroll
                for (int ct = 0; ct < 4; ct++) {
                    if (col[ct] < N) {
                        const float p = rv * sigf(acc[rt][ct][r]);
                        s += -fmaxf(__logf(1.f - p), -100.f);
                    }
                }
                s = qreduce16(s);
                if (l16 == 0) part[(size_t)row * pstride + pslot] = s;
            }
        }
    }
}

// cvt x->bf16 (blocks 0..191) + exact fp32 root logits (blocks 192..447)
__global__ __launch_bounds__(256) void k_pre(const float* __restrict__ x,
                                             const float* __restrict__ headW,
                                             __hip_bfloat16* __restrict__ xb,
                                             float* __restrict__ rootlogit) {
    const int bx = blockIdx.x;
    if (bx < 192) {
        const int i = (bx * 256 + threadIdx.x) * 4;
        const float4 v = *(const float4*)(x + i);
        s16x4 o;
        o[0] = bfc(v.x); o[1] = bfc(v.y); o[2] = bfc(v.z); o[3] = bfc(v.w);
        *(s16x4*)(xb + i) = o;
    } else {
        const int row = bx - 192;
        const int wave = threadIdx.x >> 6, lane = threadIdx.x & 63;
        if (wave < 3) {
            const float* xr = x + row * INF;
            const float* wr = headW + (size_t)(NSHORT + wave) * INF;
            float s = 0.f;
            for (int k = lane; k < INF; k += 64) s += xr[k] * wr[k];
            s = wreduce64(s);
            if (lane == 0) rootlogit[row * 3 + wave] = s;
        }
    }
}

// head softplus partials (32 blocks) + w1 GEMMs (11 blocks)
__global__ __launch_bounds__(256, 2) void k_mm1(const __hip_bfloat16* __restrict__ xb,
                                                const float* __restrict__ headW,
                                                const float* w10, const float* w11, const float* w12,
                                                float* __restrict__ phead,
                                                float* h0, float* h1, float* h2) {
    const int bx = blockIdx.x;
    if (bx < 32) {
        core_gemm<24, 1>(xb, headW, NHEAD, bx, nullptr, 0, phead, 32, bx, nullptr, 0);
    } else if (bx < 38) {
        core_gemm<24, 0>(xb, w10, 384, bx - 32, h0, 384, nullptr, 0, 0, nullptr, 0);
    } else if (bx < 41) {
        core_gemm<24, 0>(xb, w11, 192, bx - 38, h1, 192, nullptr, 0, 0, nullptr, 0);
    } else {
        core_gemm<24, 0>(xb, w12, 96, bx - 41, h2, 96, nullptr, 0, 0, nullptr, 0);
    }
}

__global__ __launch_bounds__(256) void k_ln(const float* h0, const float* h1, const float* h2,
                                            const float* g0, const float* g1, const float* g2,
                                            const float* b0, const float* b1, const float* b2,
                                            __hip_bfloat16* o0, __hip_bfloat16* o1,
                                            __hip_bfloat16* o2) {
    const int task = blockIdx.x * 4 + (threadIdx.x >> 6);  // 0..767
    const int ci = task >> 8, row = task & 255, lane = threadIdx.x & 63;
    const float *h, *g, *bb; __hip_bfloat16* o; int hsz;
    if (ci == 0)      { h = h0; g = g0; bb = b0; o = o0; hsz = 384; }
    else if (ci == 1) { h = h1; g = g1; bb = b1; o = o1; hsz = 192; }
    else              { h = h2; g = g2; bb = b2; o = o2; hsz = 96;  }
    const float* hr = h + row * hsz;
    float s = 0.f, s2 = 0.f;
    for (int k = lane; k < hsz; k += 64) { const float v = hr[k]; s += v; s2 += v * v; }
    s = wreduce64(s); s2 = wreduce64(s2);
    const float mu = s / hsz;
    const float var = s2 / hsz - mu * mu;
    const float rsn = rsqrtf(var + 1e-5f);
    for (int k = lane; k < hsz; k += 64) {
        const float v = (hr[k] - mu) * rsn * g[k] + bb[k];
        o[row * hsz + k] = __float2bfloat16(fmaxf(v, 0.f));
    }
}

// corr (256 blocks, first) + BCE dense partials (1533 stripe blocks)
__global__ __launch_bounds__(256, 2) void k_bce(const __hip_bfloat16* hb0,
                                                const __hip_bfloat16* hb1,
                                                const __hip_bfloat16* hb2,
                                                const float* w20, const float* w21, const float* w22,
                                                float* __restrict__ part,
                                                const float* __restrict__ rootlogit,
                                                const float* __restrict__ x,
                                                const float* __restrict__ headW,
                                                const int* __restrict__ target,
                                                float* __restrict__ corrbuf) {
    const int bx = blockIdx.x;
    if (bx >= 256) {
        const int gb = bx - 256;
        if (gb < 157)
            core_gemm<12, 2>(hb0, w20, 10000, gb, nullptr, 0,
                             part, PSTRIDE, gb, rootlogit, 0);
        else if (gb < 595)
            core_gemm<6, 2>(hb1, w21, 28000, gb - 157, nullptr, 0,
                            part, PSTRIDE, gb, rootlogit, 1);
        else
            core_gemm<3, 2>(hb2, w22, 60000, gb - 595, nullptr, 0,
                            part, PSTRIDE, gb, rootlogit, 2);
    } else {   // corrections: one block per row
        const int row = bx;
        const int t = threadIdx.x, wave = t >> 6, lane = t & 63;
        __shared__ float sx[INF];
        __shared__ __hip_bfloat16 shb[384 + 192 + 96];
        __shared__ int st[20];
        __shared__ float scorr[4];  // [0..2] cluster corr, [3] head corr
        for (int i = t; i < INF; i += 256) sx[i] = x[row * INF + i];
        for (int i = t; i < 384; i += 256) shb[i] = hb0[row * 384 + i];
        for (int i = t; i < 192; i += 256) shb[384 + i] = hb1[row * 192 + i];
        for (int i = t; i < 96; i += 256)  shb[576 + i] = hb2[row * 96 + i];
        if (t < 20) st[t] = target[row * 20 + t];
        if (t < 4) scorr[t] = 0.f;
        __syncthreads();
        for (int l = wave; l < 20; l += 4) {
            const int tg = st[l];
            bool dup = false;
            for (int m = 0; m < l; m++) dup |= (st[m] == tg);
            if (dup) continue;
            if (tg < NSHORT) {
                const float* wr = headW + (size_t)tg * INF;
                float z = 0.f;
                for (int k = lane; k < INF; k += 64) z += sx[k] * wr[k];
                z = wreduce64(z);
                if (lane == 0) atomicAdd(&scorr[3], -z);
            } else {
                int ci, low, hsz, hoff; const float* w2;
                if (tg < 12000)      { ci = 0; low = 2000;  hsz = 384; hoff = 0;   w2 = w20; }
                else if (tg < 40000) { ci = 1; low = 12000; hsz = 192; hoff = 384; w2 = w21; }
                else                 { ci = 2; low = 40000; hsz = 96;  hoff = 576; w2 = w22; }
                const float* wr = w2 + (size_t)(tg - low) * hsz;
                float z = 0.f;
                for (int k = lane; k < hsz; k += 64)
                    z += __bfloat162float(shb[hoff + k]) * wr[k];
                z = wreduce64(z);
                if (lane == 0) {
                    const float rvv = sigf(rootlogit[row * 3 + ci]);
                    const float p = rvv * sigf(z);
                    atomicAdd(&scorr[ci],
                              -fmaxf(__logf(p), -100.f) + fmaxf(__logf(1.f - p), -100.f));
                }
            }
        }
        __syncthreads();
        if (t < 4) corrbuf[row * 4 + t] = scorr[t];
    }
}

// Per-row finalize: reduce 1533 partials + 32 head partials, activity logic, mean.
__global__ __launch_bounds__(256) void k_red(const float* __restrict__ part,
                                             const float* __restrict__ phead,
                                             const float* __restrict__ corrbuf,
                                             const float* __restrict__ rootlogit,
                                             const int* __restrict__ target,
                                             float* __restrict__ out) {
    const int row = blockIdx.x, t = threadIdx.x;
    const int wave = t >> 6, lane = t & 63;
    const float* pr = part + (size_t)row * PSTRIDE;
    float c0 = 0.f, c1 = 0.f, c2 = 0.f, hs = 0.f;
    for (int i = t; i < 1533; i += 256) {
        const float v = pr[i];
        if (i < 157) c0 += v; else if (i < 595) c1 += v; else c2 += v;
    }
    if (t < 32) hs = phead[row * 32 + t];
    c0 = wreduce64(c0); c1 = wreduce64(c1); c2 = wreduce64(c2); hs = wreduce64(hs);
    __shared__ float red[4][4];
    if (lane == 0) { red[0][wave] = c0; red[1][wave] = c1; red[2][wave] = c2; red[3][wave] = hs; }
    __syncthreads();
    if (t == 0) {
        float cc[3];
        for (int i = 0; i < 3; i++) cc[i] = red[i][0] + red[i][1] + red[i][2] + red[i][3];
        float hsum = red[3][0] + red[3][1] + red[3][2] + red[3][3] + corrbuf[row * 4 + 3];
        bool act[3] = {false, false, false};
        for (int l = 0; l < 20; l++) {
            const int tg = target[row * 20 + l];
            if (tg >= 2000) {
                if (tg < 12000) act[0] = true;
                else if (tg < 40000) act[1] = true;
                else act[2] = true;
            }
        }
        float total = 0.f, num = 2000.f;
        const float csz[3] = {10000.f, 28000.f, 60000.f};
        for (int i = 0; i < 3; i++) {
            if (act[i]) { total += cc[i] + corrbuf[row * 4 + i]; num += csz[i]; }
            else        { hsum += softplusf(rootlogit[row * 3 + i]); num += 1.f; }
        }
        atomicAdd(out, (hsum + total) / num * (1.f / 256.f));
    }
}

extern "C" void kernel_launch(void* const* d_in, const int* in_sizes, int n_in,
                              void* d_out, int out_size, void* d_ws, size_t ws_size,
                              hipStream_t stream) {
    const float* x      = (const float*)d_in[0];
    const float* headW  = (const float*)d_in[1];
    const int*   target = (const int*)d_in[2];
    const float* w10 = (const float*)d_in[3];
    const float* g0  = (const float*)d_in[4];
    const float* b0  = (const float*)d_in[5];
    const float* w20 = (const float*)d_in[6];
    const float* w11 = (const float*)d_in[7];
    const float* g1  = (const float*)d_in[8];
    const float* b1  = (const float*)d_in[9];
    const float* w21 = (const float*)d_in[10];
    const float* w12 = (const float*)d_in[11];
    const float* g2  = (const float*)d_in[12];
    const float* b2  = (const float*)d_in[13];
    const float* w22 = (const float*)d_in[14];
    float* out = (float*)d_out;

    char* ws = (char*)d_ws;
    size_t off = 0;
    auto carve = [&](size_t bytes) -> void* {
        void* p = ws + off;
        off += (bytes + 255) & ~(size_t)255;
        return p;
    };
    __hip_bfloat16* xb  = (__hip_bfloat16*)carve((size_t)256 * INF * 2);
    float* h0           = (float*)carve((size_t)256 * 384 * 4);
    float* h1           = (float*)carve((size_t)256 * 192 * 4);
    float* h2           = (float*)carve((size_t)256 * 96 * 4);
    __hip_bfloat16* hb0 = (__hip_bfloat16*)carve((size_t)256 * 384 * 2);
    __hip_bfloat16* hb1 = (__hip_bfloat16*)carve((size_t)256 * 192 * 2);
    __hip_bfloat16* hb2 = (__hip_bfloat16*)carve((size_t)256 * 96 * 2);
    float* rootlogit    = (float*)carve((size_t)256 * 3 * 4);
    float* phead        = (float*)carve((size_t)256 * 32 * 4);
    float* part         = (float*)carve((size_t)256 * PSTRIDE * 4);
    float* corrbuf      = (float*)carve((size_t)256 * 4 * 4);

    hipMemsetAsync(out, 0, sizeof(float), stream);

    k_pre<<<448, 256, 0, stream>>>(x, headW, xb, rootlogit);
    k_mm1<<<43, 256, 0, stream>>>(xb, headW, w10, w11, w12, phead, h0, h1, h2);
    k_ln<<<192, 256, 0, stream>>>(h0, h1, h2, g0, g1, g2, b0, b1, b2, hb0, hb1, hb2);
    k_bce<<<1789, 256, 0, stream>>>(hb0, hb1, hb2, w20, w21, w22, part, rootlogit,
                                    x, headW, target, corrbuf);
    k_red<<<256, 256, 0, stream>>>(part, phead, corrbuf, rootlogit, target, out);

    (void)in_sizes; (void)n_in; (void)out_size; (void)ws_size;
}

// Round 5
// 200.729 us; speedup vs baseline: 1.4076x; 1.2781x over previous
//
#include <hip/hip_runtime.h>
#include <hip/hip_bf16.h>

#define INF 768
#define NSHORT 2000
#define NHEAD 2003

typedef __attribute__((ext_vector_type(8))) short  s16x8;
typedef __attribute__((ext_vector_type(4))) float  f32x4;
typedef __attribute__((ext_vector_type(8))) float  f32x8;

__device__ __forceinline__ float sigf(float z) { return 1.f / (1.f + __expf(-z)); }
__device__ __forceinline__ float softplusf(float z) {
    return fmaxf(z, 0.f) + __logf(1.f + __expf(-fabsf(z)));
}
__device__ __forceinline__ float qreduce16(float v) {
    v += __shfl_xor(v, 1); v += __shfl_xor(v, 2);
    v += __shfl_xor(v, 4); v += __shfl_xor(v, 8);
    return v;
}
__device__ __forceinline__ float wreduce64(float v) {
    v += __shfl_xor(v, 1);  v += __shfl_xor(v, 2);  v += __shfl_xor(v, 4);
    v += __shfl_xor(v, 8);  v += __shfl_xor(v, 16); v += __shfl_xor(v, 32);
    return v;
}
__device__ __forceinline__ short bfc(float x) {
    union { __hip_bfloat16 h; short s; } u; u.h = __float2bfloat16(x); return u.s;
}

// ---- fragment-order permutation helpers (run in massively parallel k_pre) ----
// B-operand: chunk c = ((stripe*K32 + j)*4 + ct)*64 + lane  holds
//   W[col][k0..k0+8) with col = stripe*64+ct*16+(lane&15) (clamped), k0 = j*32+(lane>>4)*8
template <int K32>
__device__ __forceinline__ void perm_B(const float* __restrict__ W, int N,
                                       __hip_bfloat16* __restrict__ dst, int c) {
    const int lane = c & 63, t2 = c >> 6;
    const int ct = t2 & 3, t3 = t2 >> 2;
    const int j = t3 % K32, stripe = t3 / K32;
    int col = stripe * 64 + ct * 16 + (lane & 15);
    if (col >= N) col = N - 1;
    const int k0 = j * 32 + (lane >> 4) * 8;
    const f32x8 v = *(const f32x8*)(W + (size_t)col * (K32 * 32) + k0);
    s16x8 o;
#pragma unroll
    for (int i = 0; i < 8; i++) o[i] = bfc(v[i]);
    *(s16x8*)((short*)dst + (size_t)c * 8) = o;
}
// A-operand: chunk c = (rt*K32 + j)*64 + lane holds A[rt*16+(lane&15)][k0..k0+8)
template <int K32>
__device__ __forceinline__ void perm_A(const float* __restrict__ X,
                                       __hip_bfloat16* __restrict__ dst, int c) {
    const int lane = c & 63, t2 = c >> 6;
    const int j = t2 % K32, rt = t2 / K32;
    const int row = rt * 16 + (lane & 15);
    const int k0 = j * 32 + (lane >> 4) * 8;
    const f32x8 v = *(const f32x8*)(X + (size_t)row * (K32 * 32) + k0);
    s16x8 o;
#pragma unroll
    for (int i = 0; i < 8; i++) o[i] = bfc(v[i]);
    *(s16x8*)((short*)dst + (size_t)c * 8) = o;
}

// ---- streaming MFMA GEMM on fragment-linear operands ----
// Block covers RT*4 row-tiles (rtb0 base); wave owns RT tiles (RT*16 rows) x 64 cols.
// All loads are 64-lane x 16B contiguous. Register double-buffer, no LDS, no barriers.
// MODE 0: store h f32. MODE 1: phead[row*32+stripe] = rowsum softplus (col<NSHORT).
// MODE 2: part[slot*256+row] = rowsum -max(log1p(-r*sig(z)),-100).
template <int K32, int RT, int MODE>
__device__ __forceinline__ void core_p(
    const __hip_bfloat16* __restrict__ Ap,
    const __hip_bfloat16* __restrict__ Wp, int N,
    int stripe, int rtb0,
    float* __restrict__ outH, int ldH,
    float* __restrict__ part, int pslot,
    const float* __restrict__ rootlogit, int ci)
{
    const int t = threadIdx.x;
    const int wave = t >> 6, lane = t & 63;
    const int quad = lane >> 4, l16 = lane & 15;
    const int rtb = rtb0 + wave * RT;

    const short* ap[RT];
#pragma unroll
    for (int rt = 0; rt < RT; rt++)
        ap[rt] = (const short*)Ap + ((size_t)(rtb + rt) * K32 * 64 + lane) * 8;
    const short* wp[4];
#pragma unroll
    for (int ct = 0; ct < 4; ct++)
        wp[ct] = (const short*)Wp + (((size_t)stripe * K32 * 4 + ct) * 64 + lane) * 8;

    s16x8 af[2][RT], wf[2][4];
#pragma unroll
    for (int rt = 0; rt < RT; rt++) af[0][rt] = *(const s16x8*)(ap[rt]);
#pragma unroll
    for (int ct = 0; ct < 4; ct++) wf[0][ct] = *(const s16x8*)(wp[ct]);

    f32x4 acc[RT][4];
#pragma unroll
    for (int rt = 0; rt < RT; rt++)
#pragma unroll
        for (int ct = 0; ct < 4; ct++) acc[rt][ct] = (f32x4){0.f, 0.f, 0.f, 0.f};

#pragma unroll
    for (int j = 0; j < K32; j++) {
        const int b = j & 1, nb = b ^ 1;
        if (j + 1 < K32) {
#pragma unroll
            for (int rt = 0; rt < RT; rt++)
                af[nb][rt] = *(const s16x8*)(ap[rt] + (size_t)(j + 1) * 512);
#pragma unroll
            for (int ct = 0; ct < 4; ct++)
                wf[nb][ct] = *(const s16x8*)(wp[ct] + (size_t)(j + 1) * 2048);
        }
#pragma unroll
        for (int rt = 0; rt < RT; rt++)
#pragma unroll
            for (int ct = 0; ct < 4; ct++)
                acc[rt][ct] = __builtin_amdgcn_mfma_f32_16x16x32_bf16(
                    af[b][rt], wf[b][ct], acc[rt][ct], 0, 0, 0);
    }

    const int col0 = stripe * 64;
    if (MODE == 0) {
#pragma unroll
        for (int rt = 0; rt < RT; rt++)
#pragma unroll
            for (int ct = 0; ct < 4; ct++) {
                const int col = col0 + ct * 16 + l16;
#pragma unroll
                for (int r = 0; r < 4; r++)
                    outH[(size_t)((rtb + rt) * 16 + quad * 4 + r) * ldH + col] = acc[rt][ct][r];
            }
    } else if (MODE == 1) {
#pragma unroll
        for (int rt = 0; rt < RT; rt++) {
#pragma unroll
            for (int r = 0; r < 4; r++) {
                const int row = (rtb + rt) * 16 + quad * 4 + r;
                float s = 0.f;
#pragma unroll
                for (int ct = 0; ct < 4; ct++) {
                    const int col = col0 + ct * 16 + l16;
                    if (col < NSHORT) s += softplusf(acc[rt][ct][r]);
                }
                s = qreduce16(s);
                if (l16 == 0) part[(size_t)row * 32 + pslot] = s;
            }
        }
    } else {
#pragma unroll
        for (int rt = 0; rt < RT; rt++) {
#pragma unroll
            for (int r = 0; r < 4; r++) {
                const int row = (rtb + rt) * 16 + quad * 4 + r;
                const float rv = sigf(rootlogit[row * 3 + ci]);
                float s = 0.f;
#pragma unroll
                for (int ct = 0; ct < 4; ct++) {
                    const int col = col0 + ct * 16 + l16;
                    if (col < N) {
                        const float p = rv * sigf(acc[rt][ct][r]);
                        s += -fmaxf(__logf(1.f - p), -100.f);
                    }
                }
                s = qreduce16(s);
                if (l16 == 0) part[(size_t)pslot * 256 + row] = s;
            }
        }
    }
}

// roots (256) + permute x (96) + headW (768) + w1 (144+72+48) + w2 (1884+2628+2814)
__global__ __launch_bounds__(256) void k_pre(
    const float* __restrict__ x, const float* __restrict__ headW,
    const float* __restrict__ w10, const float* __restrict__ w11, const float* __restrict__ w12,
    const float* __restrict__ w20, const float* __restrict__ w21, const float* __restrict__ w22,
    __hip_bfloat16* xbp, __hip_bfloat16* hWp,
    __hip_bfloat16* w10p, __hip_bfloat16* w11p, __hip_bfloat16* w12p,
    __hip_bfloat16* w20p, __hip_bfloat16* w21p, __hip_bfloat16* w22p,
    float* __restrict__ rootlogit) {
    const int bx = blockIdx.x, t = threadIdx.x;
    if (bx < 256) {
        const int row = bx, wave = t >> 6, lane = t & 63;
        if (wave < 3) {
            const float* xr = x + row * INF;
            const float* wr = headW + (size_t)(NSHORT + wave) * INF;
            float s = 0.f;
            for (int k = lane; k < INF; k += 64) s += xr[k] * wr[k];
            s = wreduce64(s);
            if (lane == 0) rootlogit[row * 3 + wave] = s;
        }
    } else if (bx < 352)  perm_A<24>(x, xbp, (bx - 256) * 256 + t);
    else if (bx < 1120) perm_B<24>(headW, NHEAD, hWp, (bx - 352) * 256 + t);
    else if (bx < 1264) perm_B<24>(w10, 384, w10p, (bx - 1120) * 256 + t);
    else if (bx < 1336) perm_B<24>(w11, 192, w11p, (bx - 1264) * 256 + t);
    else if (bx < 1384) perm_B<24>(w12, 96, w12p, (bx - 1336) * 256 + t);
    else if (bx < 3268) perm_B<12>(w20, 10000, w20p, (bx - 1384) * 256 + t);
    else if (bx < 5896) perm_B<6>(w21, 28000, w21p, (bx - 3268) * 256 + t);
    else                perm_B<3>(w22, 60000, w22p, (bx - 5896) * 256 + t);
}

// head softplus partials (64 blocks: 32 stripes x 2 rowgroups) + w1 GEMMs (22 blocks)
__global__ __launch_bounds__(256) void k_mm1(const __hip_bfloat16* __restrict__ xbp,
                                             const __hip_bfloat16* hWp,
                                             const __hip_bfloat16* w10p,
                                             const __hip_bfloat16* w11p,
                                             const __hip_bfloat16* w12p,
                                             float* __restrict__ phead,
                                             float* h0, float* h1, float* h2) {
    const int bx = blockIdx.x;
    if (bx < 64) {
        const int stripe = bx >> 1, rg = bx & 1;
        core_p<24, 2, 1>(xbp, hWp, NHEAD, stripe, rg * 8, nullptr, 0, phead, stripe, nullptr, 0);
    } else if (bx < 76) {
        const int m = bx - 64, stripe = m >> 1, rg = m & 1;
        core_p<24, 2, 0>(xbp, w10p, 384, stripe, rg * 8, h0, 384, nullptr, 0, nullptr, 0);
    } else if (bx < 82) {
        const int m = bx - 76, stripe = m >> 1, rg = m & 1;
        core_p<24, 2, 0>(xbp, w11p, 192, stripe, rg * 8, h1, 192, nullptr, 0, nullptr, 0);
    } else {
        const int m = bx - 82, stripe = m >> 1, rg = m & 1;
        core_p<24, 2, 0>(xbp, w12p, 96, stripe, rg * 8, h2, 96, nullptr, 0, nullptr, 0);
    }
}

// LayerNorm+ReLU -> bf16, written BOTH flat (for corr) and fragment-permuted (for GEMM)
__global__ __launch_bounds__(256) void k_ln(const float* h0, const float* h1, const float* h2,
                                            const float* g0, const float* g1, const float* g2,
                                            const float* b0, const float* b1, const float* b2,
                                            __hip_bfloat16* f0, __hip_bfloat16* f1,
                                            __hip_bfloat16* f2,
                                            __hip_bfloat16* p0, __hip_bfloat16* p1,
                                            __hip_bfloat16* p2) {
    const int task = blockIdx.x * 4 + (threadIdx.x >> 6);  // 0..767
    const int ci = task >> 8, row = task & 255, lane = threadIdx.x & 63;
    const float *h, *g, *bb; __hip_bfloat16 *fo, *po; int hsz, K32;
    if (ci == 0)      { h = h0; g = g0; bb = b0; fo = f0; po = p0; hsz = 384; K32 = 12; }
    else if (ci == 1) { h = h1; g = g1; bb = b1; fo = f1; po = p1; hsz = 192; K32 = 6; }
    else              { h = h2; g = g2; bb = b2; fo = f2; po = p2; hsz = 96;  K32 = 3; }
    const float* hr = h + row * hsz;
    float s = 0.f, s2 = 0.f;
    for (int k = lane; k < hsz; k += 64) { const float v = hr[k]; s += v; s2 += v * v; }
    s = wreduce64(s); s2 = wreduce64(s2);
    const float mu = s / hsz;
    const float var = s2 / hsz - mu * mu;
    const float rsn = rsqrtf(var + 1e-5f);
    const int nch = hsz >> 3;
    if (lane < nch) {
        const f32x8 v = *(const f32x8*)(hr + lane * 8);
        const f32x8 gg = *(const f32x8*)(g + lane * 8);
        const f32x8 bv = *(const f32x8*)(bb + lane * 8);
        s16x8 o;
#pragma unroll
        for (int i = 0; i < 8; i++)
            o[i] = bfc(fmaxf((v[i] - mu) * rsn * gg[i] + bv[i], 0.f));
        *(s16x8*)((short*)fo + (size_t)row * hsz + lane * 8) = o;
        // permuted: rt=row>>4, l16=row&15, k0=lane*8 -> j=lane>>2, q=lane&3
        const size_t chunk = ((size_t)(row >> 4) * K32 + (lane >> 2)) * 64 + (lane & 3) * 16 + (row & 15);
        *(s16x8*)((short*)po + chunk * 8) = o;
    }
}

// corr (256 blocks) + BCE dense partials (1533 stripe blocks)
__global__ __launch_bounds__(256, 2) void k_bce(const __hip_bfloat16* p0,
                                                const __hip_bfloat16* p1,
                                                const __hip_bfloat16* p2,
                                                const __hip_bfloat16* w20p,
                                                const __hip_bfloat16* w21p,
                                                const __hip_bfloat16* w22p,
                                                const __hip_bfloat16* f0,
                                                const __hip_bfloat16* f1,
                                                const __hip_bfloat16* f2,
                                                const float* w20, const float* w21, const float* w22,
                                                float* __restrict__ part,
                                                const float* __restrict__ rootlogit,
                                                const float* __restrict__ x,
                                                const float* __restrict__ headW,
                                                const int* __restrict__ target,
                                                float* __restrict__ corrbuf) {
    const int bx = blockIdx.x;
    if (bx >= 256) {
        const int gb = bx - 256;
        if (gb < 157)
            core_p<12, 4, 2>(p0, w20p, 10000, gb, 0, nullptr, 0, part, gb, rootlogit, 0);
        else if (gb < 595)
            core_p<6, 4, 2>(p1, w21p, 28000, gb - 157, 0, nullptr, 0, part, gb, rootlogit, 1);
        else
            core_p<3, 4, 2>(p2, w22p, 60000, gb - 595, 0, nullptr, 0, part, gb, rootlogit, 2);
    } else {
        const int row = bx;
        const int t = threadIdx.x, wave = t >> 6, lane = t & 63;
        __shared__ float sx[INF];
        __shared__ __hip_bfloat16 shb[384 + 192 + 96];
        __shared__ int st[20];
        __shared__ float scorr[4];
        for (int i = t; i < INF; i += 256) sx[i] = x[row * INF + i];
        for (int i = t; i < 384; i += 256) shb[i] = f0[row * 384 + i];
        for (int i = t; i < 192; i += 256) shb[384 + i] = f1[row * 192 + i];
        for (int i = t; i < 96; i += 256)  shb[576 + i] = f2[row * 96 + i];
        if (t < 20) st[t] = target[row * 20 + t];
        if (t < 4) scorr[t] = 0.f;
        __syncthreads();
        for (int l = wave; l < 20; l += 4) {
            const int tg = st[l];
            bool dup = false;
            for (int m = 0; m < l; m++) dup |= (st[m] == tg);
            if (dup) continue;
            if (tg < NSHORT) {
                const float* wr = headW + (size_t)tg * INF;
                float z = 0.f;
                for (int k = lane; k < INF; k += 64) z += sx[k] * wr[k];
                z = wreduce64(z);
                if (lane == 0) atomicAdd(&scorr[3], -z);
            } else {
                int ci, low, hsz, hoff; const float* w2;
                if (tg < 12000)      { ci = 0; low = 2000;  hsz = 384; hoff = 0;   w2 = w20; }
                else if (tg < 40000) { ci = 1; low = 12000; hsz = 192; hoff = 384; w2 = w21; }
                else                 { ci = 2; low = 40000; hsz = 96;  hoff = 576; w2 = w22; }
                const float* wr = w2 + (size_t)(tg - low) * hsz;
                float z = 0.f;
                for (int k = lane; k < hsz; k += 64)
                    z += __bfloat162float(shb[hoff + k]) * wr[k];
                z = wreduce64(z);
                if (lane == 0) {
                    const float rvv = sigf(rootlogit[row * 3 + ci]);
                    const float p = rvv * sigf(z);
                    atomicAdd(&scorr[ci],
                              -fmaxf(__logf(p), -100.f) + fmaxf(__logf(1.f - p), -100.f));
                }
            }
        }
        __syncthreads();
        if (t < 4) corrbuf[row * 4 + t] = scorr[t];
    }
}

__global__ __launch_bounds__(256) void k_red(const float* __restrict__ part,
                                             const float* __restrict__ phead,
                                             const float* __restrict__ corrbuf,
                                             const float* __restrict__ rootlogit,
                                             const int* __restrict__ target,
                                             float* __restrict__ out) {
    const int row = blockIdx.x, t = threadIdx.x;
    const int wave = t >> 6, lane = t & 63;
    float c0 = 0.f, c1 = 0.f, c2 = 0.f, hs = 0.f;
    for (int i = t; i < 1533; i += 256) {
        const float v = part[(size_t)i * 256 + row];
        if (i < 157) c0 += v; else if (i < 595) c1 += v; else c2 += v;
    }
    if (t < 32) hs = phead[row * 32 + t];
    c0 = wreduce64(c0); c1 = wreduce64(c1); c2 = wreduce64(c2); hs = wreduce64(hs);
    __shared__ float red[4][4];
    if (lane == 0) { red[0][wave] = c0; red[1][wave] = c1; red[2][wave] = c2; red[3][wave] = hs; }
    __syncthreads();
    if (t == 0) {
        float cc[3];
        for (int i = 0; i < 3; i++) cc[i] = red[i][0] + red[i][1] + red[i][2] + red[i][3];
        float hsum = red[3][0] + red[3][1] + red[3][2] + red[3][3] + corrbuf[row * 4 + 3];
        bool act[3] = {false, false, false};
        for (int l = 0; l < 20; l++) {
            const int tg = target[row * 20 + l];
            if (tg >= 2000) {
                if (tg < 12000) act[0] = true;
                else if (tg < 40000) act[1] = true;
                else act[2] = true;
            }
        }
        float total = 0.f, num = 2000.f;
        const float csz[3] = {10000.f, 28000.f, 60000.f};
        for (int i = 0; i < 3; i++) {
            if (act[i]) { total += cc[i] + corrbuf[row * 4 + i]; num += csz[i]; }
            else        { hsum += softplusf(rootlogit[row * 3 + i]); num += 1.f; }
        }
        atomicAdd(out, (hsum + total) / num * (1.f / 256.f));
    }
}

extern "C" void kernel_launch(void* const* d_in, const int* in_sizes, int n_in,
                              void* d_out, int out_size, void* d_ws, size_t ws_size,
                              hipStream_t stream) {
    const float* x      = (const float*)d_in[0];
    const float* headW  = (const float*)d_in[1];
    const int*   target = (const int*)d_in[2];
    const float* w10 = (const float*)d_in[3];
    const float* g0  = (const float*)d_in[4];
    const float* b0  = (const float*)d_in[5];
    const float* w20 = (const float*)d_in[6];
    const float* w11 = (const float*)d_in[7];
    const float* g1  = (const float*)d_in[8];
    const float* b1  = (const float*)d_in[9];
    const float* w21 = (const float*)d_in[10];
    const float* w12 = (const float*)d_in[11];
    const float* g2  = (const float*)d_in[12];
    const float* b2  = (const float*)d_in[13];
    const float* w22 = (const float*)d_in[14];
    float* out = (float*)d_out;

    char* ws = (char*)d_ws;
    size_t off = 0;
    auto carve = [&](size_t bytes) -> void* {
        void* p = ws + off;
        off += (bytes + 255) & ~(size_t)255;
        return p;
    };
    __hip_bfloat16* xbp  = (__hip_bfloat16*)carve((size_t)256 * 768 * 2);
    __hip_bfloat16* hWp  = (__hip_bfloat16*)carve((size_t)2048 * 768 * 2);
    __hip_bfloat16* w10p = (__hip_bfloat16*)carve((size_t)384 * 768 * 2);
    __hip_bfloat16* w11p = (__hip_bfloat16*)carve((size_t)192 * 768 * 2);
    __hip_bfloat16* w12p = (__hip_bfloat16*)carve((size_t)128 * 768 * 2);
    __hip_bfloat16* w20p = (__hip_bfloat16*)carve((size_t)10048 * 384 * 2);
    __hip_bfloat16* w21p = (__hip_bfloat16*)carve((size_t)28032 * 192 * 2);
    __hip_bfloat16* w22p = (__hip_bfloat16*)carve((size_t)60032 * 96 * 2);
    float* h0            = (float*)carve((size_t)256 * 384 * 4);
    float* h1            = (float*)carve((size_t)256 * 192 * 4);
    float* h2            = (float*)carve((size_t)256 * 96 * 4);
    __hip_bfloat16* f0   = (__hip_bfloat16*)carve((size_t)256 * 384 * 2);
    __hip_bfloat16* f1   = (__hip_bfloat16*)carve((size_t)256 * 192 * 2);
    __hip_bfloat16* f2   = (__hip_bfloat16*)carve((size_t)256 * 96 * 2);
    __hip_bfloat16* p0   = (__hip_bfloat16*)carve((size_t)256 * 384 * 2);
    __hip_bfloat16* p1   = (__hip_bfloat16*)carve((size_t)256 * 192 * 2);
    __hip_bfloat16* p2   = (__hip_bfloat16*)carve((size_t)256 * 96 * 2);
    float* rootlogit     = (float*)carve((size_t)256 * 3 * 4);
    float* phead         = (float*)carve((size_t)256 * 32 * 4);
    float* part          = (float*)carve((size_t)1536 * 256 * 4);
    float* corrbuf       = (float*)carve((size_t)256 * 4 * 4);

    hipMemsetAsync(out, 0, sizeof(float), stream);

    k_pre<<<8710, 256, 0, stream>>>(x, headW, w10, w11, w12, w20, w21, w22,
                                    xbp, hWp, w10p, w11p, w12p, w20p, w21p, w22p,
                                    rootlogit);
    k_mm1<<<86, 256, 0, stream>>>(xbp, hWp, w10p, w11p, w12p, phead, h0, h1, h2);
    k_ln<<<192, 256, 0, stream>>>(h0, h1, h2, g0, g1, g2, b0, b1, b2,
                                  f0, f1, f2, p0, p1, p2);
    k_bce<<<1789, 256, 0, stream>>>(p0, p1, p2, w20p, w21p, w22p, f0, f1, f2,
                                    w20, w21, w22, part, rootlogit, x, headW,
                                    target, corrbuf);
    k_red<<<256, 256, 0, stream>>>(part, phead, corrbuf, rootlogit, target, out);

    (void)in_sizes; (void)n_in; (void)out_size; (void)ws_size;
}

// Round 6
// 186.076 us; speedup vs baseline: 1.5185x; 1.0788x over previous
//
#include <hip/hip_runtime.h>
#include <hip/hip_bf16.h>

#define INF 768
#define NSHORT 2000
#define NHEAD 2003

typedef __attribute__((ext_vector_type(8))) short  s16x8;
typedef __attribute__((ext_vector_type(4))) float  f32x4;
typedef __attribute__((ext_vector_type(8))) float  f32x8;

__device__ __forceinline__ float sigf(float z) { return 1.f / (1.f + __expf(-z)); }
__device__ __forceinline__ float softplusf(float z) {
    return fmaxf(z, 0.f) + __logf(1.f + __expf(-fabsf(z)));
}
__device__ __forceinline__ float qreduce16(float v) {
    v += __shfl_xor(v, 1); v += __shfl_xor(v, 2);
    v += __shfl_xor(v, 4); v += __shfl_xor(v, 8);
    return v;
}
__device__ __forceinline__ float wreduce64(float v) {
    v += __shfl_xor(v, 1);  v += __shfl_xor(v, 2);  v += __shfl_xor(v, 4);
    v += __shfl_xor(v, 8);  v += __shfl_xor(v, 16); v += __shfl_xor(v, 32);
    return v;
}
__device__ __forceinline__ short bfc(float x) {
    union { __hip_bfloat16 h; short s; } u; u.h = __float2bfloat16(x); return u.s;
}

// ---- fragment-order permutation helpers ----
template <int K32>
__device__ __forceinline__ void perm_B(const float* __restrict__ W, int N,
                                       __hip_bfloat16* __restrict__ dst, int c) {
    const int lane = c & 63, t2 = c >> 6;
    const int ct = t2 & 3, t3 = t2 >> 2;
    const int j = t3 % K32, stripe = t3 / K32;
    int col = stripe * 64 + ct * 16 + (lane & 15);
    if (col >= N) col = N - 1;
    const int k0 = j * 32 + (lane >> 4) * 8;
    const f32x8 v = *(const f32x8*)(W + (size_t)col * (K32 * 32) + k0);
    s16x8 o;
#pragma unroll
    for (int i = 0; i < 8; i++) o[i] = bfc(v[i]);
    *(s16x8*)((short*)dst + (size_t)c * 8) = o;
}
template <int K32>
__device__ __forceinline__ void perm_A(const float* __restrict__ X,
                                       __hip_bfloat16* __restrict__ dst, int c) {
    const int lane = c & 63, t2 = c >> 6;
    const int j = t2 % K32, rt = t2 / K32;
    const int row = rt * 16 + (lane & 15);
    const int k0 = j * 32 + (lane >> 4) * 8;
    const f32x8 v = *(const f32x8*)(X + (size_t)row * (K32 * 32) + k0);
    s16x8 o;
#pragma unroll
    for (int i = 0; i < 8; i++) o[i] = bfc(v[i]);
    *(s16x8*)((short*)dst + (size_t)c * 8) = o;
}

// ---- streaming MFMA GEMM on fragment-linear operands ----
// Block = 4 waves x (RT*16 rows) x 64 cols; rtb0 = base row-tile; split-K via j0/kstr.
// MODE 0: store z (f32, col<N guarded). MODE 2: grouped-log BCE row-sums into part.
template <int K32, int RT, int MODE>
__device__ __forceinline__ void core_p(
    const __hip_bfloat16* __restrict__ Ap,
    const __hip_bfloat16* __restrict__ Wp, int N,
    int stripe, int rtb0, int j0, int kstr,
    float* __restrict__ outH, int ldH,
    float* __restrict__ part, int pslot,
    const float* __restrict__ rootlogit, int ci)
{
    const int t = threadIdx.x;
    const int wave = t >> 6, lane = t & 63;
    const int quad = lane >> 4, l16 = lane & 15;
    const int rtb = rtb0 + wave * RT;

    const short* ap[RT];
#pragma unroll
    for (int rt = 0; rt < RT; rt++)
        ap[rt] = (const short*)Ap + (((size_t)(rtb + rt) * kstr + j0) * 64 + lane) * 8;
    const short* wp[4];
#pragma unroll
    for (int ct = 0; ct < 4; ct++)
        wp[ct] = (const short*)Wp + ((((size_t)stripe * kstr + j0) * 4 + ct) * 64 + lane) * 8;

    s16x8 af[2][RT], wf[2][4];
#pragma unroll
    for (int rt = 0; rt < RT; rt++) af[0][rt] = *(const s16x8*)(ap[rt]);
#pragma unroll
    for (int ct = 0; ct < 4; ct++) wf[0][ct] = *(const s16x8*)(wp[ct]);

    f32x4 acc[RT][4];
#pragma unroll
    for (int rt = 0; rt < RT; rt++)
#pragma unroll
        for (int ct = 0; ct < 4; ct++) acc[rt][ct] = (f32x4){0.f, 0.f, 0.f, 0.f};

#pragma unroll
    for (int j = 0; j < K32; j++) {
        const int b = j & 1, nb = b ^ 1;
        if (j + 1 < K32) {
#pragma unroll
            for (int rt = 0; rt < RT; rt++)
                af[nb][rt] = *(const s16x8*)(ap[rt] + (size_t)(j + 1) * 512);
#pragma unroll
            for (int ct = 0; ct < 4; ct++)
                wf[nb][ct] = *(const s16x8*)(wp[ct] + (size_t)(j + 1) * 2048);
        }
#pragma unroll
        for (int rt = 0; rt < RT; rt++)
#pragma unroll
            for (int ct = 0; ct < 4; ct++)
                acc[rt][ct] = __builtin_amdgcn_mfma_f32_16x16x32_bf16(
                    af[b][rt], wf[b][ct], acc[rt][ct], 0, 0, 0);
    }

    const int col0 = stripe * 64;
    if (MODE == 0) {
#pragma unroll
        for (int rt = 0; rt < RT; rt++)
#pragma unroll
            for (int ct = 0; ct < 4; ct++) {
                const int col = col0 + ct * 16 + l16;
                if (col < N) {   // guard: no cross-row corruption on padded stripes
#pragma unroll
                    for (int r = 0; r < 4; r++)
                        outH[(size_t)((rtb + rt) * 16 + quad * 4 + r) * ldH + col] =
                            acc[rt][ct][r];
                }
            }
    } else {
        // sum_ct -log(1-r*sig(z)) = log prod(1+t) - log prod(1+t-r), t=e^-z
#pragma unroll
        for (int rt = 0; rt < RT; rt++) {
#pragma unroll
            for (int r = 0; r < 4; r++) {
                const int row = (rtb + rt) * 16 + quad * 4 + r;
                const float rv = sigf(rootlogit[row * 3 + ci]);
                float pd = 1.f, pn = 1.f;
#pragma unroll
                for (int ct = 0; ct < 4; ct++) {
                    const int col = col0 + ct * 16 + l16;
                    const float tv = fminf(__expf(-acc[rt][ct][r]), 1e6f);
                    const float d = (col < N) ? (1.f + tv) : 1.f;
                    const float n = (col < N) ? (1.f + tv - rv) : 1.f;
                    pd *= d; pn *= n;
                }
                float s = __logf(pd) - __logf(pn);
                s = qreduce16(s);
                if (l16 == 0) part[(size_t)pslot * 256 + row] = s;
            }
        }
    }
}

// roots (256) + permute x (96) + headW (768) + w1 (144+72+48) + w2 (1884+2628+2814)
__global__ __launch_bounds__(256) void k_pre(
    const float* __restrict__ x, const float* __restrict__ headW,
    const float* __restrict__ w10, const float* __restrict__ w11, const float* __restrict__ w12,
    const float* __restrict__ w20, const float* __restrict__ w21, const float* __restrict__ w22,
    __hip_bfloat16* xbp, __hip_bfloat16* hWp,
    __hip_bfloat16* w10p, __hip_bfloat16* w11p, __hip_bfloat16* w12p,
    __hip_bfloat16* w20p, __hip_bfloat16* w21p, __hip_bfloat16* w22p,
    float* __restrict__ rootlogit) {
    const int bx = blockIdx.x, t = threadIdx.x;
    if (bx < 256) {
        const int row = bx, wave = t >> 6, lane = t & 63;
        if (wave < 3) {
            const float* xr = x + row * INF;
            const float* wr = headW + (size_t)(NSHORT + wave) * INF;
            float s = 0.f;
            for (int k = lane; k < INF; k += 64) s += xr[k] * wr[k];
            s = wreduce64(s);
            if (lane == 0) rootlogit[row * 3 + wave] = s;
        }
    } else if (bx < 352)  perm_A<24>(x, xbp, (bx - 256) * 256 + t);
    else if (bx < 1120) perm_B<24>(headW, NHEAD, hWp, (bx - 352) * 256 + t);
    else if (bx < 1264) perm_B<24>(w10, 384, w10p, (bx - 1120) * 256 + t);
    else if (bx < 1336) perm_B<24>(w11, 192, w11p, (bx - 1264) * 256 + t);
    else if (bx < 1384) perm_B<24>(w12, 96, w12p, (bx - 1336) * 256 + t);
    else if (bx < 3268) perm_B<12>(w20, 10000, w20p, (bx - 1384) * 256 + t);
    else if (bx < 5896) perm_B<6>(w21, 28000, w21p, (bx - 3268) * 256 + t);
    else                perm_B<3>(w22, 60000, w22p, (bx - 5896) * 256 + t);
}

// split-K GEMMs: head z-partials (128 blocks) + w1 h-partials (44 blocks)
__global__ __launch_bounds__(256, 4) void k_mm1(const __hip_bfloat16* __restrict__ xbp,
                                                const __hip_bfloat16* hWp,
                                                const __hip_bfloat16* w10p,
                                                const __hip_bfloat16* w11p,
                                                const __hip_bfloat16* w12p,
                                                float* zA, float* zB,
                                                float* h0a, float* h0b,
                                                float* h1a, float* h1b,
                                                float* h2a, float* h2b) {
    const int bx = blockIdx.x;
    if (bx < 128) {   // head: stripe 32 x rg 2 x kq 2
        const int kq = bx & 1, rg = (bx >> 1) & 1, stripe = bx >> 2;
        core_p<12, 2, 0>(xbp, hWp, NHEAD, stripe, rg * 8, kq * 12, 24,
                         kq ? zB : zA, 2048, nullptr, 0, nullptr, 0);
    } else if (bx < 152) {
        const int m = bx - 128, stripe = m >> 2, rg = (m >> 1) & 1, kq = m & 1;
        core_p<12, 2, 0>(xbp, w10p, 384, stripe, rg * 8, kq * 12, 24,
                         kq ? h0b : h0a, 384, nullptr, 0, nullptr, 0);
    } else if (bx < 164) {
        const int m = bx - 152, stripe = m >> 2, rg = (m >> 1) & 1, kq = m & 1;
        core_p<12, 2, 0>(xbp, w11p, 192, stripe, rg * 8, kq * 12, 24,
                         kq ? h1b : h1a, 192, nullptr, 0, nullptr, 0);
    } else {
        const int m = bx - 164, stripe = m >> 2, rg = (m >> 1) & 1, kq = m & 1;
        core_p<12, 2, 0>(xbp, w12p, 96, stripe, rg * 8, kq * 12, 24,
                         kq ? h2b : h2a, 96, nullptr, 0, nullptr, 0);
    }
}

// ln (192 blocks) + head softplus row-sums (256 blocks)
__global__ __launch_bounds__(256) void k_ln(const float* h0a, const float* h0b,
                                            const float* h1a, const float* h1b,
                                            const float* h2a, const float* h2b,
                                            const float* g0, const float* g1, const float* g2,
                                            const float* b0, const float* b1, const float* b2,
                                            const float* zA, const float* zB,
                                            __hip_bfloat16* f0, __hip_bfloat16* f1,
                                            __hip_bfloat16* f2,
                                            __hip_bfloat16* p0, __hip_bfloat16* p1,
                                            __hip_bfloat16* p2,
                                            float* __restrict__ phead) {
    const int bx = blockIdx.x;
    if (bx < 192) {
        const int task = bx * 4 + (threadIdx.x >> 6);  // 0..767
        const int ci = task >> 8, row = task & 255, lane = threadIdx.x & 63;
        const float *ha, *hb, *g, *bb; __hip_bfloat16 *fo, *po; int hsz, K32;
        if (ci == 0)      { ha = h0a; hb = h0b; g = g0; bb = b0; fo = f0; po = p0; hsz = 384; K32 = 12; }
        else if (ci == 1) { ha = h1a; hb = h1b; g = g1; bb = b1; fo = f1; po = p1; hsz = 192; K32 = 6; }
        else              { ha = h2a; hb = h2b; g = g2; bb = b2; fo = f2; po = p2; hsz = 96;  K32 = 3; }
        const float* hra = ha + row * hsz;
        const float* hrb = hb + row * hsz;
        float s = 0.f, s2 = 0.f;
        for (int k = lane; k < hsz; k += 64) {
            const float v = hra[k] + hrb[k]; s += v; s2 += v * v;
        }
        s = wreduce64(s); s2 = wreduce64(s2);
        const float mu = s / hsz;
        const float var = s2 / hsz - mu * mu;
        const float rsn = rsqrtf(var + 1e-5f);
        const int nch = hsz >> 3;
        if (lane < nch) {
            const f32x8 va = *(const f32x8*)(hra + lane * 8);
            const f32x8 vb = *(const f32x8*)(hrb + lane * 8);
            const f32x8 gg = *(const f32x8*)(g + lane * 8);
            const f32x8 bv = *(const f32x8*)(bb + lane * 8);
            s16x8 o;
#pragma unroll
            for (int i = 0; i < 8; i++)
                o[i] = bfc(fmaxf((va[i] + vb[i] - mu) * rsn * gg[i] + bv[i], 0.f));
            *(s16x8*)((short*)fo + (size_t)row * hsz + lane * 8) = o;
            const size_t chunk = ((size_t)(row >> 4) * K32 + (lane >> 2)) * 64
                               + (lane & 3) * 16 + (row & 15);
            *(s16x8*)((short*)po + chunk * 8) = o;
        }
    } else {
        // head softplus: sum_{col<2000} softplus(zA+zB); grouped log
        const int row = bx - 192, t = threadIdx.x;
        const int wave = t >> 6, lane = t & 63;
        float val = 0.f;
        if (t < 250) {
            const f32x8 a = *(const f32x8*)(zA + (size_t)row * 2048 + t * 8);
            const f32x8 b = *(const f32x8*)(zB + (size_t)row * 2048 + t * 8);
            float m = 0.f, P = 1.f;
#pragma unroll
            for (int i = 0; i < 8; i++) {
                const float z = a[i] + b[i];
                m += fmaxf(z, 0.f);
                P *= 1.f + __expf(-fabsf(z));
            }
            val = m + __logf(P);
        }
        val = wreduce64(val);
        __shared__ float red[4];
        if (lane == 0) red[wave] = val;
        __syncthreads();
        if (t == 0) phead[row] = red[0] + red[1] + red[2] + red[3];
    }
}

// pure GEMM BCE partials: 1533 stripes x 2 rowgroups = 3066 blocks
__global__ __launch_bounds__(256, 4) void k_bce(const __hip_bfloat16* p0,
                                                const __hip_bfloat16* p1,
                                                const __hip_bfloat16* p2,
                                                const __hip_bfloat16* w20p,
                                                const __hip_bfloat16* w21p,
                                                const __hip_bfloat16* w22p,
                                                float* __restrict__ part,
                                                const float* __restrict__ rootlogit) {
    const int bx = blockIdx.x;
    const int s = bx >> 1, rg = bx & 1;
    if (s < 157)
        core_p<12, 2, 2>(p0, w20p, 10000, s, rg * 8, 0, 12,
                         nullptr, 0, part, s, rootlogit, 0);
    else if (s < 595)
        core_p<6, 2, 2>(p1, w21p, 28000, s - 157, rg * 8, 0, 6,
                        nullptr, 0, part, s, rootlogit, 1);
    else
        core_p<3, 2, 2>(p2, w22p, 60000, s - 595, rg * 8, 0, 3,
                        nullptr, 0, part, s, rootlogit, 2);
}

// per-row: target corrections + partial reduction + final mean
__global__ __launch_bounds__(256) void k_red(const float* __restrict__ part,
                                             const float* __restrict__ phead,
                                             const float* __restrict__ rootlogit,
                                             const int* __restrict__ target,
                                             const float* __restrict__ x,
                                             const float* __restrict__ headW,
                                             const __hip_bfloat16* f0,
                                             const __hip_bfloat16* f1,
                                             const __hip_bfloat16* f2,
                                             const float* w20, const float* w21, const float* w22,
                                             float* __restrict__ out) {
    const int row = blockIdx.x;
    const int t = threadIdx.x, wave = t >> 6, lane = t & 63;
    __shared__ float sx[INF];
    __shared__ __hip_bfloat16 shb[384 + 192 + 96];
    __shared__ int st[20];
    __shared__ float scorr[4];
    __shared__ float red[4][4];
    for (int i = t; i < INF; i += 256) sx[i] = x[row * INF + i];
    for (int i = t; i < 384; i += 256) shb[i] = f0[row * 384 + i];
    for (int i = t; i < 192; i += 256) shb[384 + i] = f1[row * 192 + i];
    for (int i = t; i < 96; i += 256)  shb[576 + i] = f2[row * 96 + i];
    if (t < 20) st[t] = target[row * 20 + t];
    if (t < 4) scorr[t] = 0.f;
    __syncthreads();
    for (int l = wave; l < 20; l += 4) {
        const int tg = st[l];
        bool dup = false;
        for (int m = 0; m < l; m++) dup |= (st[m] == tg);
        if (dup) continue;
        if (tg < NSHORT) {
            const float* wr = headW + (size_t)tg * INF;
            float z = 0.f;
            for (int k = lane; k < INF; k += 64) z += sx[k] * wr[k];
            z = wreduce64(z);
            if (lane == 0) atomicAdd(&scorr[3], -z);
        } else {
            int ci, low, hsz, hoff; const float* w2;
            if (tg < 12000)      { ci = 0; low = 2000;  hsz = 384; hoff = 0;   w2 = w20; }
            else if (tg < 40000) { ci = 1; low = 12000; hsz = 192; hoff = 384; w2 = w21; }
            else                 { ci = 2; low = 40000; hsz = 96;  hoff = 576; w2 = w22; }
            const float* wr = w2 + (size_t)(tg - low) * hsz;
            float z = 0.f;
            for (int k = lane; k < hsz; k += 64)
                z += __bfloat162float(shb[hoff + k]) * wr[k];
            z = wreduce64(z);
            if (lane == 0) {
                const float rvv = sigf(rootlogit[row * 3 + ci]);
                const float p = rvv * sigf(z);
                atomicAdd(&scorr[ci],
                          -fmaxf(__logf(p), -100.f) + fmaxf(__logf(1.f - p), -100.f));
            }
        }
    }
    // dense-partial reduction
    float c0 = 0.f, c1 = 0.f, c2 = 0.f;
    for (int i = t; i < 1533; i += 256) {
        const float v = part[(size_t)i * 256 + row];
        if (i < 157) c0 += v; else if (i < 595) c1 += v; else c2 += v;
    }
    c0 = wreduce64(c0); c1 = wreduce64(c1); c2 = wreduce64(c2);
    if (lane == 0) { red[0][wave] = c0; red[1][wave] = c1; red[2][wave] = c2; }
    __syncthreads();
    if (t == 0) {
        float cc[3];
        for (int i = 0; i < 3; i++) cc[i] = red[i][0] + red[i][1] + red[i][2] + red[i][3];
        float hsum = phead[row] + scorr[3];
        bool act[3] = {false, false, false};
        for (int l = 0; l < 20; l++) {
            const int tg = target[row * 20 + l];
            if (tg >= 2000) {
                if (tg < 12000) act[0] = true;
                else if (tg < 40000) act[1] = true;
                else act[2] = true;
            }
        }
        float total = 0.f, num = 2000.f;
        const float csz[3] = {10000.f, 28000.f, 60000.f};
        for (int i = 0; i < 3; i++) {
            if (act[i]) { total += cc[i] + scorr[i]; num += csz[i]; }
            else        { hsum += softplusf(rootlogit[row * 3 + i]); num += 1.f; }
        }
        atomicAdd(out, (hsum + total) / num * (1.f / 256.f));
    }
}

extern "C" void kernel_launch(void* const* d_in, const int* in_sizes, int n_in,
                              void* d_out, int out_size, void* d_ws, size_t ws_size,
                              hipStream_t stream) {
    const float* x      = (const float*)d_in[0];
    const float* headW  = (const float*)d_in[1];
    const int*   target = (const int*)d_in[2];
    const float* w10 = (const float*)d_in[3];
    const float* g0  = (const float*)d_in[4];
    const float* b0  = (const float*)d_in[5];
    const float* w20 = (const float*)d_in[6];
    const float* w11 = (const float*)d_in[7];
    const float* g1  = (const float*)d_in[8];
    const float* b1  = (const float*)d_in[9];
    const float* w21 = (const float*)d_in[10];
    const float* w12 = (const float*)d_in[11];
    const float* g2  = (const float*)d_in[12];
    const float* b2  = (const float*)d_in[13];
    const float* w22 = (const float*)d_in[14];
    float* out = (float*)d_out;

    char* ws = (char*)d_ws;
    size_t off = 0;
    auto carve = [&](size_t bytes) -> void* {
        void* p = ws + off;
        off += (bytes + 255) & ~(size_t)255;
        return p;
    };
    __hip_bfloat16* xbp  = (__hip_bfloat16*)carve((size_t)256 * 768 * 2);
    __hip_bfloat16* hWp  = (__hip_bfloat16*)carve((size_t)2048 * 768 * 2);
    __hip_bfloat16* w10p = (__hip_bfloat16*)carve((size_t)384 * 768 * 2);
    __hip_bfloat16* w11p = (__hip_bfloat16*)carve((size_t)192 * 768 * 2);
    __hip_bfloat16* w12p = (__hip_bfloat16*)carve((size_t)128 * 768 * 2);
    __hip_bfloat16* w20p = (__hip_bfloat16*)carve((size_t)10048 * 384 * 2);
    __hip_bfloat16* w21p = (__hip_bfloat16*)carve((size_t)28032 * 192 * 2);
    __hip_bfloat16* w22p = (__hip_bfloat16*)carve((size_t)60032 * 96 * 2);
    float* zA            = (float*)carve((size_t)256 * 2048 * 4);
    float* zB            = (float*)carve((size_t)256 * 2048 * 4);
    float* h0a           = (float*)carve((size_t)256 * 384 * 4);
    float* h0b           = (float*)carve((size_t)256 * 384 * 4);
    float* h1a           = (float*)carve((size_t)256 * 192 * 4);
    float* h1b           = (float*)carve((size_t)256 * 192 * 4);
    float* h2a           = (float*)carve((size_t)256 * 96 * 4);
    float* h2b           = (float*)carve((size_t)256 * 96 * 4);
    __hip_bfloat16* f0   = (__hip_bfloat16*)carve((size_t)256 * 384 * 2);
    __hip_bfloat16* f1   = (__hip_bfloat16*)carve((size_t)256 * 192 * 2);
    __hip_bfloat16* f2   = (__hip_bfloat16*)carve((size_t)256 * 96 * 2);
    __hip_bfloat16* p0   = (__hip_bfloat16*)carve((size_t)256 * 384 * 2);
    __hip_bfloat16* p1   = (__hip_bfloat16*)carve((size_t)256 * 192 * 2);
    __hip_bfloat16* p2   = (__hip_bfloat16*)carve((size_t)256 * 96 * 2);
    float* rootlogit     = (float*)carve((size_t)256 * 3 * 4);
    float* phead         = (float*)carve((size_t)256 * 4);
    float* part          = (float*)carve((size_t)1536 * 256 * 4);

    hipMemsetAsync(out, 0, sizeof(float), stream);

    k_pre<<<8710, 256, 0, stream>>>(x, headW, w10, w11, w12, w20, w21, w22,
                                    xbp, hWp, w10p, w11p, w12p, w20p, w21p, w22p,
                                    rootlogit);
    k_mm1<<<172, 256, 0, stream>>>(xbp, hWp, w10p, w11p, w12p,
                                   zA, zB, h0a, h0b, h1a, h1b, h2a, h2b);
    k_ln<<<448, 256, 0, stream>>>(h0a, h0b, h1a, h1b, h2a, h2b,
                                  g0, g1, g2, b0, b1, b2, zA, zB,
                                  f0, f1, f2, p0, p1, p2, phead);
    k_bce<<<3066, 256, 0, stream>>>(p0, p1, p2, w20p, w21p, w22p, part, rootlogit);
    k_red<<<256, 256, 0, stream>>>(part, phead, rootlogit, target, x, headW,
                                   f0, f1, f2, w20, w21, w22, out);

    (void)in_sizes; (void)n_in; (void)out_size; (void)ws_size;
}